// Round 16
// baseline (193.638 us; speedup 1.0000x reference)
//
#include <hip/hip_runtime.h>

#define NN 50000          // nodes
#define NE 800000         // edges (without self loops)
#define NE2 (NE + NN)     // edges + self loops
#define CSRN (NE + 2 * NN) // csr slots: per node [counter][self][reals]
#define FD 128            // input feature dim
#define HD 128            // hidden dim
#define NHD 4             // heads
#define OD 512            // heads * HD
#define NG 512            // graphs
#define BN_EPS 1e-5f

#define SCAN_CHUNK 2048
#define EB_CHUNK 4096
#define NB_F ((NE + EB_CHUNK - 1) / EB_CHUNK)      // 196 edge chunks
#define NBUCK ((NN + 511) / 512)                   // 98 node buckets (512 nodes)
#define NH (NBUCK * NB_F)                          // 19208 counters
#define NB2 ((NH + SCAN_CHUNK - 1) / SCAN_CHUNK)   // 10 scan blocks
#define CAPR 13312                                 // LDS stage ints (52KB)

#define WG_BLOCKS (FD * HD / 256)                  // 64
#define WA_BLOCKS (HD * OD / 256)                  // 256
#define CP_WGT0 7
#define CP_WGATT0 (CP_WGT0 + WG_BLOCKS)            // 71
#define CP_ZROW (CP_WGATT0 + WA_BLOCKS)            // 327
#define CP_GST0 (CP_ZROW + 1)                      // 328
#define CP_FZ0 (CP_GST0 + 3)                       // 331
#define CP_NB (CP_FZ0 + 768)                       // 1099

typedef __attribute__((ext_vector_type(8))) short bfrag;   // 8 bf16 = 4 VGPRs
typedef __attribute__((ext_vector_type(4))) float f32x4;
typedef __attribute__((ext_vector_type(2))) float f32x2;
typedef unsigned short ushort_t;

__device__ inline ushort_t f2bf(float f) {               // RNE fp32->bf16
    unsigned int u = __float_as_uint(f);
    unsigned int r = (u + 0x7fffu + ((u >> 16) & 1u)) >> 16;
    return (ushort_t)r;
}
__device__ inline float bf2f_lo(unsigned int v) { return __uint_as_float(v << 16); }
__device__ inline float bf2f_hi(unsigned int v) { return __uint_as_float(v & 0xffff0000u); }

// ---------------- CSR build: bucket-staged, no global atomics ----------------
__global__ __launch_bounds__(256) void histA_k(const int* __restrict__ ei,
                                               int* __restrict__ hist) {
    __shared__ int h[NBUCK];
    int blk = blockIdx.x, t = threadIdx.x;
    for (int i = t; i < NBUCK; i += 256) h[i] = 0;
    __syncthreads();
    int e0 = blk * EB_CHUNK;
    for (int i = t; i < EB_CHUNK; i += 256) {
        int e = e0 + i;
        if (e < NE) atomicAdd(&h[ei[NE + e] >> 9], 1);
    }
    __syncthreads();
    for (int i = t; i < NBUCK; i += 256) hist[i * NB_F + blk] = h[i];
}

__global__ __launch_bounds__(256) void scanA2_k(const int* __restrict__ hist,
                                                int* __restrict__ bsum2) {
    __shared__ int red[256];
    int b = blockIdx.x, t = threadIdx.x;
    int base = b * SCAN_CHUNK + t * 8;
    int s = 0;
    #pragma unroll
    for (int i = 0; i < 8; ++i) { int idx = base + i; if (idx < NH) s += hist[idx]; }
    red[t] = s;
    __syncthreads();
    for (int off = 128; off; off >>= 1) {
        if (t < off) red[t] += red[t + off];
        __syncthreads();
    }
    if (t == 0) bsum2[b] = red[0];
}

__global__ __launch_bounds__(256) void scanC2_k(const int* __restrict__ hist,
                                                const int* __restrict__ bsum2,
                                                int* __restrict__ base) {
    __shared__ int red[256];
    __shared__ int boff_s;
    int b = blockIdx.x, t = threadIdx.x;
    if (t == 0) {
        int run = 0;
        for (int i = 0; i < b; ++i) run += bsum2[i];
        boff_s = run;
    }
    int bse = b * SCAN_CHUNK + t * 8;
    int v[8];
    int s = 0;
    #pragma unroll
    for (int i = 0; i < 8; ++i) {
        int idx = bse + i;
        v[i] = (idx < NH) ? hist[idx] : 0;
        s += v[i];
    }
    red[t] = s;
    __syncthreads();
    for (int off = 1; off < 256; off <<= 1) {
        int y = (t >= off) ? red[t - off] : 0;
        __syncthreads();
        red[t] += y;
        __syncthreads();
    }
    int run = boff_s + red[t] - s;
    #pragma unroll
    for (int i = 0; i < 8; ++i) {
        int idx = bse + i;
        if (idx < NH) { base[idx] = run; run += v[i]; }
    }
    if (b == 0 && t == 0) base[NH] = NE;
}

__global__ __launch_bounds__(256) void scatter2_k(const int* __restrict__ ei,
                                                  const int* __restrict__ base,
                                                  int2* __restrict__ ebuf) {
    __shared__ int cur[NBUCK];
    int blk = blockIdx.x, t = threadIdx.x;
    for (int i = t; i < NBUCK; i += 256) cur[i] = base[i * NB_F + blk];
    __syncthreads();
    int e0 = blk * EB_CHUNK;
    for (int i = t; i < EB_CHUNK; i += 256) {
        int e = e0 + i;
        if (e < NE) {
            int src = ei[e], dst = ei[NE + e];
            int pos = atomicAdd(&cur[dst >> 9], 1);
            ebuf[pos] = make_int2(src, dst);
        }
    }
}

__global__ __launch_bounds__(256) void bfill_k(const int2* __restrict__ ebuf,
                                               const int* __restrict__ base,
                                               int* __restrict__ rowptr,
                                               float* __restrict__ dis,
                                               int* __restrict__ csr) {
    __shared__ int cnt[512];
    __shared__ int pref[512];
    __shared__ int red[256];
    __shared__ int stage[CAPR];
    int b = blockIdx.x, t = threadIdx.x;
    int n0 = b * 512;
    int nn = min(512, NN - n0);
    int eb0 = base[b * NB_F];
    int eb1 = base[(b + 1) * NB_F];
    int ecnt = eb1 - eb0;
    int gbase = eb0 + 2 * n0;
    for (int i = t; i < nn; i += 256) cnt[i] = 0;
    __syncthreads();
    for (int e = eb0 + t; e < eb1; e += 256)
        atomicAdd(&cnt[ebuf[e].y - n0], 1);
    __syncthreads();
    int i0 = 2 * t, i1 = 2 * t + 1;
    int v0 = (i0 < nn) ? cnt[i0] + 2 : 0;
    int v1 = (i1 < nn) ? cnt[i1] + 2 : 0;
    int ps = v0 + v1;
    red[t] = ps;
    __syncthreads();
    for (int off = 1; off < 256; off <<= 1) {
        int y = (t >= off) ? red[t - off] : 0;
        __syncthreads();
        red[t] += y;
        __syncthreads();
    }
    int excl = red[t] - ps;
    if (i0 < nn) pref[i0] = excl;
    if (i1 < nn) pref[i1] = excl + v0;
    __syncthreads();
    int region = ecnt + 2 * nn;
    for (int i = t; i < nn; i += 256) {
        rowptr[n0 + i] = gbase + pref[i];
        dis[n0 + i] = rsqrtf((float)(cnt[i] + 1));
    }
    if (b == 0 && t == 0) rowptr[NN] = CSRN;
    __syncthreads();
    for (int i = t; i < nn; i += 256) cnt[i] = 0;
    __syncthreads();
    if (region <= CAPR) {
        for (int i = t; i < nn; i += 256) {
            int r = pref[i];
            stage[r] = 0;
            stage[r + 1] = n0 + i;
        }
        __syncthreads();
        for (int e = eb0 + t; e < eb1; e += 256) {
            int2 ed = ebuf[e];
            int l = ed.y - n0;
            int pos = atomicAdd(&cnt[l], 1);
            stage[pref[l] + 2 + pos] = ed.x;
        }
        __syncthreads();
        for (int i = t; i < region; i += 256) csr[gbase + i] = stage[i];
    } else {
        for (int i = t; i < nn; i += 256) {
            int r = gbase + pref[i];
            csr[r] = 0;
            csr[r + 1] = n0 + i;
        }
        __syncthreads();
        for (int e = eb0 + t; e < eb1; e += 256) {
            int2 ed = ebuf[e];
            int l = ed.y - n0;
            int pos = atomicAdd(&cnt[l], 1);
            csr[gbase + pref[l] + 2 + pos] = ed.x;
        }
    }
}

// ---------------- merged: BN affine + waT + weight casts + zero-row + gstart + feat zero
__global__ __launch_bounds__(256) void castprep_k(
    const float* __restrict__ b_gcn, const float* __restrict__ g2_gam,
    const float* __restrict__ g2_bet, const float* __restrict__ g2_mean,
    const float* __restrict__ g2_var, const float* __restrict__ b_gat,
    const float* __restrict__ g1_gam, const float* __restrict__ g1_bet,
    const float* __restrict__ g1_mean, const float* __restrict__ g1_var,
    float* __restrict__ Ag, float* __restrict__ Bg,
    float* __restrict__ Aa, float* __restrict__ Ba,
    const float* __restrict__ a_src, const float* __restrict__ a_dst,
    float* __restrict__ waT,
    const float* __restrict__ w_gcn, ushort_t* __restrict__ wgT,
    const float* __restrict__ w_gat, ushort_t* __restrict__ wgatT,
    ushort_t* __restrict__ h0b, const int* __restrict__ batch,
    int* __restrict__ gstart, float* __restrict__ feat) {
    int b = blockIdx.x, tid = threadIdx.x;
    if (b < 3) {
        int t = b * 256 + tid;
        if (t < HD) {
            float a = rsqrtf(g2_var[t] + BN_EPS) * g2_gam[t];
            Ag[t] = a;
            Bg[t] = (b_gcn[t] - g2_mean[t]) * a + g2_bet[t];
        } else if (t < HD + OD) {
            int d = t - HD;
            float a = rsqrtf(g1_var[d] + BN_EPS) * g1_gam[d];
            Aa[d] = a;
            Ba[d] = (b_gat[d] - g1_mean[d]) * a + g1_bet[d];
        }
    } else if (b < 7) {
        int t = (b - 3) * 256 + tid;       // 0..1023
        int k = t >> 3, j = t & 7, head = j & 3;
        const float* av = (j < 4 ? a_src : a_dst) + head * 128;
        const float* w = w_gat + (size_t)k * OD + head * 128;
        float s = 0.f;
        for (int d = 0; d < 128; ++d) s += w[d] * av[d];
        waT[j * 128 + k] = s;
    } else if (b < CP_WGATT0) {
        int t = (b - CP_WGT0) * 256 + tid;       // K=FD, N=HD
        int n = t / FD, k = t - n * FD;
        wgT[n * FD + k] = f2bf(w_gcn[k * HD + n]);
    } else if (b < CP_ZROW) {
        int t = (b - CP_WGATT0) * 256 + tid;   // K=HD, N=OD
        int n = t / HD, k = t - n * HD;
        wgatT[n * HD + k] = f2bf(w_gat[k * OD + n]);
    } else if (b == CP_ZROW) {
        if (tid < 64) ((unsigned int*)(h0b + (size_t)NN * HD))[tid] = 0u;
    } else if (b < CP_FZ0) {
        int g = (b - CP_GST0) * 256 + tid;
        if (g <= NG) {
            int lo = 0, hi = NN;
            while (lo < hi) { int mid = (lo + hi) >> 1; if (batch[mid] < g) lo = mid + 1; else hi = mid; }
            gstart[g] = lo;
        }
    } else {
        int t = (b - CP_FZ0) * 256 + tid;       // 768*256 threads, 4 floats each
        float4 z = make_float4(0.f, 0.f, 0.f, 0.f);
        *(float4*)(feat + 4 * (size_t)t) = z;
    }
}

// ---------------- bf16 MFMA GEMM reading fp32 A (cast fused into staging), row-scale out
__global__ __launch_bounds__(256) void gemm_x_k(const float* __restrict__ A,
                                                const ushort_t* __restrict__ BT,
                                                const float* __restrict__ rowscale,
                                                ushort_t* __restrict__ C,
                                                int M, int N) {
    __shared__ short As[128][136];
    __shared__ short Bs[64][136];
    const int tid = threadIdx.x;
    const int m0 = blockIdx.x * 128;
    const int n0 = blockIdx.y * 64;

    #pragma unroll
    for (int i = 0; i < 16; ++i) {
        int c = tid + 256 * i;
        int row = c >> 5, off = (c & 31) * 4;
        float4 v = make_float4(0.f, 0.f, 0.f, 0.f);
        if (m0 + row < M) v = *(const float4*)(A + (size_t)(m0 + row) * 128 + off);
        ushort_t o[4] = {f2bf(v.x), f2bf(v.y), f2bf(v.z), f2bf(v.w)};
        *(unsigned long long*)&As[row][off] = *(unsigned long long*)o;
    }
    #pragma unroll
    for (int i = 0; i < 4; ++i) {
        int c = tid + 256 * i;
        int row = c >> 4, off = (c & 15) * 8;
        *(bfrag*)&Bs[row][off] = *(const bfrag*)(BT + (size_t)(n0 + row) * 128 + off);
    }
    __syncthreads();

    const int w = tid >> 6;
    const int lr = tid & 15;
    const int kg = (tid & 63) >> 4;

    f32x4 acc[2][4];
    #pragma unroll
    for (int mi = 0; mi < 2; ++mi)
        #pragma unroll
        for (int ni = 0; ni < 4; ++ni) acc[mi][ni] = (f32x4)0.f;

    #pragma unroll
    for (int ks = 0; ks < 4; ++ks) {
        bfrag af[2], bb[4];
        #pragma unroll
        for (int mi = 0; mi < 2; ++mi)
            af[mi] = *(const bfrag*)&As[32 * w + 16 * mi + lr][32 * ks + 8 * kg];
        #pragma unroll
        for (int ni = 0; ni < 4; ++ni)
            bb[ni] = *(const bfrag*)&Bs[16 * ni + lr][32 * ks + 8 * kg];
        #pragma unroll
        for (int mi = 0; mi < 2; ++mi)
            #pragma unroll
            for (int ni = 0; ni < 4; ++ni)
                acc[mi][ni] = __builtin_amdgcn_mfma_f32_16x16x32_bf16(
                    af[mi], bb[ni], acc[mi][ni], 0, 0, 0);
    }

    #pragma unroll
    for (int mi = 0; mi < 2; ++mi) {
        #pragma unroll
        for (int r = 0; r < 4; ++r) {
            int row = m0 + 32 * w + 16 * mi + 4 * kg + r;
            if (row < M) {
                float sc = rowscale[row];
                #pragma unroll
                for (int ni = 0; ni < 4; ++ni) {
                    int col = n0 + 16 * ni + lr;
                    C[(size_t)row * N + col] = f2bf(acc[mi][ni][r] * sc);
                }
            }
        }
    }
}

// ---------------- per-head GEMM + BN + ReLU + fused pooling (atomic sadd/smax) ----------------
__global__ __launch_bounds__(256) void gemm_zp_k(const ushort_t* __restrict__ zb,
                                                 const ushort_t* __restrict__ wgatT,
                                                 const float* __restrict__ Aa,
                                                 const float* __restrict__ Ba,
                                                 const int* __restrict__ batch,
                                                 const int* __restrict__ gstart,
                                                 float* __restrict__ feat) {
    __shared__ short As[128][136];
    __shared__ short Bs[64][136];
    const int tid = threadIdx.x;
    const int head = blockIdx.z;
    const int m0 = blockIdx.x * 128;
    const int n0 = blockIdx.y * 64;
    const ushort_t* A = zb + (size_t)head * NN * HD;
    const ushort_t* BT = wgatT + (size_t)head * HD * HD;

    #pragma unroll
    for (int i = 0; i < 8; ++i) {
        int c = tid + 256 * i;
        int row = c >> 4, off = (c & 15) * 8;
        bfrag v = (bfrag)0;
        if (m0 + row < NN) v = *(const bfrag*)(A + (size_t)(m0 + row) * HD + off);
        *(bfrag*)&As[row][off] = v;
    }
    #pragma unroll
    for (int i = 0; i < 4; ++i) {
        int c = tid + 256 * i;
        int row = c >> 4, off = (c & 15) * 8;
        *(bfrag*)&Bs[row][off] = *(const bfrag*)(BT + (size_t)(n0 + row) * HD + off);
    }
    __syncthreads();

    const int w = tid >> 6;
    const int lr = tid & 15;
    const int kg = (tid & 63) >> 4;

    f32x4 acc[2][4];
    #pragma unroll
    for (int mi = 0; mi < 2; ++mi)
        #pragma unroll
        for (int ni = 0; ni < 4; ++ni) acc[mi][ni] = (f32x4)0.f;

    #pragma unroll
    for (int ks = 0; ks < 4; ++ks) {
        bfrag af[2], bb[4];
        #pragma unroll
        for (int mi = 0; mi < 2; ++mi)
            af[mi] = *(const bfrag*)&As[32 * w + 16 * mi + lr][32 * ks + 8 * kg];
        #pragma unroll
        for (int ni = 0; ni < 4; ++ni)
            bb[ni] = *(const bfrag*)&Bs[16 * ni + lr][32 * ks + 8 * kg];
        #pragma unroll
        for (int mi = 0; mi < 2; ++mi)
            #pragma unroll
            for (int ni = 0; ni < 4; ++ni)
                acc[mi][ni] = __builtin_amdgcn_mfma_f32_16x16x32_bf16(
                    af[mi], bb[ni], acc[mi][ni], 0, 0, 0);
    }

    __syncthreads();
    float (*vals)[65] = reinterpret_cast<float(*)[65]>(&As[0][0]);
    float (*psum)[64] = reinterpret_cast<float(*)[64]>(&Bs[0][0]);
    float (*pmax)[64] = reinterpret_cast<float(*)[64]>(&Bs[8][0]);

    #pragma unroll
    for (int mi = 0; mi < 2; ++mi) {
        #pragma unroll
        for (int r = 0; r < 4; ++r) {
            int lrow = 32 * w + 16 * mi + 4 * kg + r;
            int row = m0 + lrow;
            if (row < NN) {
                #pragma unroll
                for (int ni = 0; ni < 4; ++ni) {
                    int gc = 128 * head + n0 + 16 * ni + lr;
                    float v = fmaf(acc[mi][ni][r], Aa[gc], Ba[gc]);
                    vals[lrow][16 * ni + lr] = fmaxf(v, 0.f);
                }
            }
        }
    }
    __syncthreads();

    int rmax = min(128, NN - m0);
    int gfirst = batch[m0];
    int glast = batch[m0 + rmax - 1];
    int c = tid & 63, part = tid >> 6;
    for (int gg = gfirst; gg <= glast; ++gg) {
        int s = max(gstart[gg], m0) - m0;
        int e = min(gstart[gg + 1], m0 + rmax) - m0;
        float sm = 0.f, mx = 0.f;
        for (int r = s + part; r < e; r += 4) {
            float v = vals[r][c];
            sm += v;
            mx = fmaxf(mx, v);
        }
        psum[part][c] = sm;
        pmax[part][c] = mx;
        __syncthreads();
        if (part == 0) {
            float ts = (psum[0][c] + psum[1][c]) + (psum[2][c] + psum[3][c]);
            float tm = fmaxf(fmaxf(pmax[0][c], pmax[1][c]), fmaxf(pmax[2][c], pmax[3][c]));
            if (e > s) {
                int gc = 128 * head + n0 + c;
                atomicAdd(&feat[(size_t)gg * 1536 + gc], ts);
                atomicMax((int*)&feat[(size_t)gg * 1536 + 512 + gc], __float_as_int(tm));
            }
        }
        __syncthreads();
    }
}

// ---------------- GCN aggregate + BN + ReLU + fused attention dots (LDS index staging)
__global__ __launch_bounds__(256) void gcn_agg4_k(
    const ushort_t* __restrict__ h0, const int* __restrict__ rowptr,
    const int* __restrict__ csr, const float* __restrict__ dis,
    const float* __restrict__ Ag, const float* __restrict__ Bg,
    const float* __restrict__ waT,
    ushort_t* __restrict__ h, float* __restrict__ asrc, float* __restrict__ adst) {
    __shared__ int sis2[4][64];
    int wv = threadIdx.x >> 6;
    int lane = threadIdx.x & 63;
    int g = lane >> 4;
    int sl = lane & 15;
    int sl8 = sl * 8;
    int n = __builtin_amdgcn_readfirstlane((int)(blockIdx.x * 4) + wv);
    int r0 = __builtin_amdgcn_readfirstlane(rowptr[n]) + 1;   // skip counter slot
    int r1 = __builtin_amdgcn_readfirstlane(rowptr[n + 1]);
    const uint4* h0_u4 = (const uint4*)h0;
    f32x2 a2[4];
    #pragma unroll
    for (int q = 0; q < 4; ++q) a2[q] = (f32x2)0.f;
    uint4 hv[2];

#define GLOAD(i, ST) { int _idx = min((ST) * 4 + g, 63); \
    int _s = sis2[wv][_idx]; \
    hv[i] = h0_u4[(unsigned)_s * 16u + (unsigned)sl]; }
#define GACC(i) { \
    f32x2 _f0 = {bf2f_lo(hv[i].x), bf2f_hi(hv[i].x)}; \
    f32x2 _f1 = {bf2f_lo(hv[i].y), bf2f_hi(hv[i].y)}; \
    f32x2 _f2 = {bf2f_lo(hv[i].z), bf2f_hi(hv[i].z)}; \
    f32x2 _f3 = {bf2f_lo(hv[i].w), bf2f_hi(hv[i].w)}; \
    a2[0] += _f0; a2[1] += _f1; a2[2] += _f2; a2[3] += _f3; }

    for (int base = r0; base < r1; base += 64) {
        {
            int e = base + lane;
            int sv = csr[e];                 // csr padded +64
            sis2[wv][lane] = (e < r1) ? sv : NN;
        }
        int rem = r1 - base; if (rem > 64) rem = 64;
        int nsteps = (rem + 3) >> 2;
        GLOAD(0, 0) GLOAD(1, 1)
        for (int st = 0; st < nsteps; st += 2) {
            GACC(0) GLOAD(0, st + 2)
            GACC(1) GLOAD(1, st + 3)
        }
    }
#undef GLOAD
#undef GACC

    #pragma unroll
    for (int q = 0; q < 4; ++q) {
        f32x2 v = a2[q];
        v.x += __shfl_xor(v.x, 16); v.x += __shfl_xor(v.x, 32);
        v.y += __shfl_xor(v.y, 16); v.y += __shfl_xor(v.y, 32);
        a2[q] = v;
    }
    float a[8] = {a2[0].x, a2[0].y, a2[1].x, a2[1].y,
                  a2[2].x, a2[2].y, a2[3].x, a2[3].y};
    float t = dis[n];
    float4 A0 = *(const float4*)(Ag + sl8);
    float4 A1 = *(const float4*)(Ag + sl8 + 4);
    float4 B0 = *(const float4*)(Bg + sl8);
    float4 B1 = *(const float4*)(Bg + sl8 + 4);
    float o[8];
    o[0] = fmaxf(fmaf(a[0] * t, A0.x, B0.x), 0.f);
    o[1] = fmaxf(fmaf(a[1] * t, A0.y, B0.y), 0.f);
    o[2] = fmaxf(fmaf(a[2] * t, A0.z, B0.z), 0.f);
    o[3] = fmaxf(fmaf(a[3] * t, A0.w, B0.w), 0.f);
    o[4] = fmaxf(fmaf(a[4] * t, A1.x, B1.x), 0.f);
    o[5] = fmaxf(fmaf(a[5] * t, A1.y, B1.y), 0.f);
    o[6] = fmaxf(fmaf(a[6] * t, A1.z, B1.z), 0.f);
    o[7] = fmaxf(fmaf(a[7] * t, A1.w, B1.w), 0.f);
    if (g == 0) {
        uint4 pk;
        pk.x = (unsigned int)f2bf(o[0]) | ((unsigned int)f2bf(o[1]) << 16);
        pk.y = (unsigned int)f2bf(o[2]) | ((unsigned int)f2bf(o[3]) << 16);
        pk.z = (unsigned int)f2bf(o[4]) | ((unsigned int)f2bf(o[5]) << 16);
        pk.w = (unsigned int)f2bf(o[6]) | ((unsigned int)f2bf(o[7]) << 16);
        *(uint4*)(h + (size_t)n * HD + sl8) = pk;
    }
    const float* w0p = waT + (2 * g) * 128 + sl8;
    const float* w1p = waT + (2 * g + 1) * 128 + sl8;
    float4 wA0 = *(const float4*)(w0p);
    float4 wA1 = *(const float4*)(w0p + 4);
    float4 wB0 = *(const float4*)(w1p);
    float4 wB1 = *(const float4*)(w1p + 4);
    float p0 = o[0] * wA0.x + o[1] * wA0.y + o[2] * wA0.z + o[3] * wA0.w
             + o[4] * wA1.x + o[5] * wA1.y + o[6] * wA1.z + o[7] * wA1.w;
    float p1 = o[0] * wB0.x + o[1] * wB0.y + o[2] * wB0.z + o[3] * wB0.w
             + o[4] * wB1.x + o[5] * wB1.y + o[6] * wB1.z + o[7] * wB1.w;
    #pragma unroll
    for (int off2 = 1; off2 < 16; off2 <<= 1) {
        p0 += __shfl_xor(p0, off2);
        p1 += __shfl_xor(p1, off2);
    }
    if (sl == 0) {
        int j0 = 2 * g;
        float* d0 = (j0 < 4) ? asrc : adst;
        float* d1 = (j0 + 1 < 4) ? asrc : adst;
        d0[n * 4 + (j0 & 3)] = p0;
        d1[n * 4 + ((j0 + 1) & 3)] = p1;
    }
}

// ---------------- fused GAT: LDS p-phase + weighted gather + reduce-scatter ----------------
__global__ __launch_bounds__(256) void zgather3_k(
    const ushort_t* __restrict__ h, const int* __restrict__ rowptr,
    const int* __restrict__ csr, const float* __restrict__ asrc,
    const float* __restrict__ adst, ushort_t* __restrict__ zb) {
    __shared__ float4 p4s[4][64];
    __shared__ int sis[4][64];
    int wv = threadIdx.x >> 6;
    int lane = threadIdx.x & 63;
    int g = lane >> 4;
    int sl = lane & 15;
    int sl8 = sl * 8;
    int n = __builtin_amdgcn_readfirstlane((int)(blockIdx.x * 4) + wv);
    int r0 = __builtin_amdgcn_readfirstlane(rowptr[n]) + 1;   // skip counter slot
    int r1 = __builtin_amdgcn_readfirstlane(rowptr[n + 1]);
    const uint4* h_u4 = (const uint4*)h;
    float4 ad = *(const float4*)(adst + 4 * n);     // uniform

    f32x2 acc[4][4];                // [head][dim-pair]
    #pragma unroll
    for (int hh = 0; hh < 4; ++hh)
        #pragma unroll
        for (int q = 0; q < 4; ++q) acc[hh][q] = (f32x2)0.f;
    f32x2 s01 = (f32x2)0.f, s23 = (f32x2)0.f;

    uint4 hv[2];
    f32x2 pa[2], pb[2];

#define ZLOAD(i, ST) { int _idx = min((ST) * 4 + g, 63); \
    float4 _p = p4s[wv][_idx]; \
    int _s = sis[wv][_idx]; \
    pa[i].x = _p.x; pa[i].y = _p.y; pb[i].x = _p.z; pb[i].y = _p.w; \
    hv[i] = h_u4[(unsigned)_s * 16u + (unsigned)sl]; }
#define ZACC(i) { \
    f32x2 _f0 = {bf2f_lo(hv[i].x), bf2f_hi(hv[i].x)}; \
    f32x2 _f1 = {bf2f_lo(hv[i].y), bf2f_hi(hv[i].y)}; \
    f32x2 _f2 = {bf2f_lo(hv[i].z), bf2f_hi(hv[i].z)}; \
    f32x2 _f3 = {bf2f_lo(hv[i].w), bf2f_hi(hv[i].w)}; \
    s01 += pa[i]; s23 += pb[i]; \
    f32x2 _p0 = {pa[i].x, pa[i].x}; \
    f32x2 _p1 = {pa[i].y, pa[i].y}; \
    f32x2 _p2 = {pb[i].x, pb[i].x}; \
    f32x2 _p3 = {pb[i].y, pb[i].y}; \
    acc[0][0] = __builtin_elementwise_fma(_p0, _f0, acc[0][0]); \
    acc[0][1] = __builtin_elementwise_fma(_p0, _f1, acc[0][1]); \
    acc[0][2] = __builtin_elementwise_fma(_p0, _f2, acc[0][2]); \
    acc[0][3] = __builtin_elementwise_fma(_p0, _f3, acc[0][3]); \
    acc[1][0] = __builtin_elementwise_fma(_p1, _f0, acc[1][0]); \
    acc[1][1] = __builtin_elementwise_fma(_p1, _f1, acc[1][1]); \
    acc[1][2] = __builtin_elementwise_fma(_p1, _f2, acc[1][2]); \
    acc[1][3] = __builtin_elementwise_fma(_p1, _f3, acc[1][3]); \
    acc[2][0] = __builtin_elementwise_fma(_p2, _f0, acc[2][0]); \
    acc[2][1] = __builtin_elementwise_fma(_p2, _f1, acc[2][1]); \
    acc[2][2] = __builtin_elementwise_fma(_p2, _f2, acc[2][2]); \
    acc[2][3] = __builtin_elementwise_fma(_p2, _f3, acc[2][3]); \
    acc[3][0] = __builtin_elementwise_fma(_p3, _f0, acc[3][0]); \
    acc[3][1] = __builtin_elementwise_fma(_p3, _f1, acc[3][1]); \
    acc[3][2] = __builtin_elementwise_fma(_p3, _f2, acc[3][2]); \
    acc[3][3] = __builtin_elementwise_fma(_p3, _f3, acc[3][3]); }

    for (int base = r0; base < r1; base += 64) {
        {
            int e = base + lane;
            bool v = e < r1;
            int sv = csr[e];                 // csr padded +64
            int s = v ? sv : 0;
            float4 as = *(const float4*)(asrc + 4 * (size_t)s);
            f32x2 x01 = {as.x + ad.x, as.y + ad.y};
            f32x2 x23 = {as.z + ad.z, as.w + ad.w};
            f32x2 l01 = __builtin_elementwise_max(x01, 0.2f * x01);
            f32x2 l23 = __builtin_elementwise_max(x23, 0.2f * x23);
            float4 p;
            p.x = v ? __expf(l01.x) : 0.f;
            p.y = v ? __expf(l01.y) : 0.f;
            p.z = v ? __expf(l23.x) : 0.f;
            p.w = v ? __expf(l23.y) : 0.f;
            p4s[wv][lane] = p;
            sis[wv][lane] = s;
        }
        int rem = r1 - base; if (rem > 64) rem = 64;
        int nsteps = (rem + 3) >> 2;
        ZLOAD(0, 0) ZLOAD(1, 1)
        for (int st = 0; st < nsteps; st += 2) {
            ZACC(0) ZLOAD(0, st + 2)
            ZACC(1) ZLOAD(1, st + 3)
        }
    }
#undef ZLOAD
#undef ZACC

    bool gb0 = (g & 1) != 0;
    bool gb1 = (g & 2) != 0;
    f32x2 tot[4];
    #pragma unroll
    for (int q = 0; q < 4; ++q) {
        f32x2 sA = gb0 ? acc[0][q] : acc[1][q];
        f32x2 sB = gb0 ? acc[2][q] : acc[3][q];
        f32x2 rA, rB;
        rA.x = __shfl_xor(sA.x, 16); rA.y = __shfl_xor(sA.y, 16);
        rB.x = __shfl_xor(sB.x, 16); rB.y = __shfl_xor(sB.y, 16);
        f32x2 kA = (gb0 ? acc[1][q] : acc[0][q]) + rA;
        f32x2 kB = (gb0 ? acc[3][q] : acc[2][q]) + rB;
        f32x2 s2 = gb1 ? kA : kB;
        f32x2 r2;
        r2.x = __shfl_xor(s2.x, 32); r2.y = __shfl_xor(s2.y, 32);
        tot[q] = (gb1 ? kB : kA) + r2;
    }
    float sA1 = gb0 ? s01.x : s01.y;
    float sB1 = gb0 ? s23.x : s23.y;
    float rA1 = __shfl_xor(sA1, 16);
    float rB1 = __shfl_xor(sB1, 16);
    float kAs = (gb0 ? s01.y : s01.x) + rA1;
    float kBs = (gb0 ? s23.y : s23.x) + rB1;
    float s2s = gb1 ? kAs : kBs;
    float r2s = __shfl_xor(s2s, 32);
    float stot = (gb1 ? kBs : kAs) + r2s;
    float invg = 1.f / (stot + 1e-16f);

    unsigned int pkc[4];
    #pragma unroll
    for (int q = 0; q < 4; ++q) {
        f32x2 v = tot[q] * invg;
        pkc[q] = (unsigned int)f2bf(v.x) | ((unsigned int)f2bf(v.y) << 16);
    }
    uint4 pk = {pkc[0], pkc[1], pkc[2], pkc[3]};
    *(uint4*)(zb + (size_t)g * NN * HD + (size_t)n * HD + sl8) = pk;
}

// ---------------- head: smean from sadd/cnt, GEMV + sigmoid ----------------
__global__ __launch_bounds__(256) void head2_k(const float* __restrict__ feat,
                                               const int* __restrict__ gstart,
                                               const float* __restrict__ w_lin,
                                               const float* __restrict__ b_lin,
                                               float* __restrict__ out) {
    __shared__ float fs[1536];
    __shared__ float red[256];
    int g = blockIdx.x, t = threadIdx.x;
    int cnt = gstart[g + 1] - gstart[g];
    float inv = cnt > 0 ? 1.f / (float)cnt : 0.f;
    for (int i = t; i < 512; i += 256) {
        float sa = feat[(size_t)g * 1536 + i];
        float mx = feat[(size_t)g * 1536 + 512 + i];
        fs[i] = sa;
        fs[512 + i] = mx;
        fs[1024 + i] = sa * inv;
    }
    __syncthreads();
    int o = t & 15, part = t >> 4;
    float s = 0.f;
    int kbeg = part * 96;
    for (int k = kbeg; k < kbeg + 96; ++k) s += fs[k] * w_lin[k * 16 + o];
    red[t] = s;
    __syncthreads();
    if (t < 16) {
        float tot = b_lin[o];
        for (int p = 0; p < 16; ++p) tot += red[p * 16 + o];
        out[g * 16 + o] = 1.f / (1.f + __expf(-tot));
    }
}

extern "C" void kernel_launch(void* const* d_in, const int* in_sizes, int n_in,
                              void* d_out, int out_size, void* d_ws, size_t ws_size,
                              hipStream_t stream) {
    const float* x       = (const float*)d_in[0];
    const int*   ei      = (const int*)d_in[1];
    const int*   batch   = (const int*)d_in[2];
    const float* w_gcn   = (const float*)d_in[3];
    const float* b_gcn   = (const float*)d_in[4];
    const float* g2_gam  = (const float*)d_in[5];
    const float* g2_bet  = (const float*)d_in[6];
    const float* g2_mean = (const float*)d_in[7];
    const float* g2_var  = (const float*)d_in[8];
    const float* w_gat   = (const float*)d_in[9];
    const float* a_src   = (const float*)d_in[10];
    const float* a_dst   = (const float*)d_in[11];
    const float* b_gat   = (const float*)d_in[12];
    const float* g1_gam  = (const float*)d_in[13];
    const float* g1_bet  = (const float*)d_in[14];
    const float* g1_mean = (const float*)d_in[15];
    const float* g1_var  = (const float*)d_in[16];
    const float* w_lin   = (const float*)d_in[17];
    const float* b_lin   = (const float*)d_in[18];
    float* out = (float*)d_out;

    char* ws = (char*)d_ws;
    size_t off = 0;
    auto alloc = [&](size_t bytes) -> void* {
        void* p = ws + off;
        off += (bytes + 255) & ~(size_t)255;
        return p;
    };
    int* hist       = (int*)alloc((size_t)NH * 4);
    int* bsum2      = (int*)alloc((size_t)NB2 * 4);
    int* base       = (int*)alloc((size_t)(NH + 1) * 4);
    int2* ebuf      = (int2*)alloc((size_t)NE * 8);
    int* rowptr     = (int*)alloc((size_t)(NN + 1) * 4);
    int* csr        = (int*)alloc((size_t)(CSRN + 64) * 4);  // +64 pad: unclamped slot reads
    int* gstart     = (int*)alloc((size_t)(NG + 1) * 4);
    float* dis      = (float*)alloc((size_t)NN * 4);
    ushort_t* wgT   = (ushort_t*)alloc((size_t)FD * HD * 2);
    ushort_t* wgatT = (ushort_t*)alloc((size_t)HD * OD * 2);
    ushort_t* h0b   = (ushort_t*)alloc((size_t)(NN + 1) * HD * 2);   // +1 zero row
    ushort_t* hb    = (ushort_t*)alloc((size_t)NN * HD * 2);
    ushort_t* zb    = (ushort_t*)alloc((size_t)NHD * NN * HD * 2);
    float* asrc     = (float*)alloc((size_t)NN * 4 * 4);
    float* adst     = (float*)alloc((size_t)NN * 4 * 4);
    float* waT      = (float*)alloc((size_t)8 * 128 * 4);
    float* Ag       = (float*)alloc((size_t)HD * 4);
    float* Bg       = (float*)alloc((size_t)HD * 4);
    float* Aa       = (float*)alloc((size_t)OD * 4);
    float* Ba       = (float*)alloc((size_t)OD * 4);
    float* feat     = (float*)alloc((size_t)NG * 1536 * 4);

    // CSR build: bucket-staged, no global atomics
    histA_k<<<NB_F, 256, 0, stream>>>(ei, hist);
    scanA2_k<<<NB2, 256, 0, stream>>>(hist, bsum2);
    scanC2_k<<<NB2, 256, 0, stream>>>(hist, bsum2, base);
    scatter2_k<<<NB_F, 256, 0, stream>>>(ei, base, ebuf);
    bfill_k<<<NBUCK, 256, 0, stream>>>(ebuf, base, rowptr, dis, csr);

    // merged BN affine + waT + weight casts + h0 zero-row + gstart + feat zero
    castprep_k<<<CP_NB, 256, 0, stream>>>(
        b_gcn, g2_gam, g2_bet, g2_mean, g2_var,
        b_gat, g1_gam, g1_bet, g1_mean, g1_var,
        Ag, Bg, Aa, Ba, a_src, a_dst, waT,
        w_gcn, wgT, w_gat, wgatT, h0b, batch, gstart, feat);

    // GCN linear: h0' = dis-row-scaled (x @ w_gcn); fp32 A cast fused into staging
    gemm_x_k<<<dim3((NN + 127) / 128, HD / 64), 256, 0, stream>>>(
        x, wgT, dis, h0b, NN, HD);

    // GCN aggregate + BN2 + ReLU + attention dots (wave per node, LDS index staging)
    gcn_agg4_k<<<NN / 4, 256, 0, stream>>>(h0b, rowptr, csr, dis, Ag, Bg, waT,
                                           hb, asrc, adst);

    // fused GAT softmax + gather (wave per node, LDS p-phase)
    zgather3_k<<<NN / 4, 256, 0, stream>>>(hb, rowptr, csr, asrc, adst, zb);

    // per-head GEMM + BN1 + ReLU + fused pooling -> feat (atomics)
    gemm_zp_k<<<dim3((NN + 127) / 128, HD / 64, NHD), 256, 0, stream>>>(
        zb, wgatT, Aa, Ba, batch, gstart, feat);

    // head (smean derived from sadd/cnt)
    head2_k<<<NG, 256, 0, stream>>>(feat, gstart, w_lin, b_lin, out);
}

// Round 17
// 189.330 us; speedup vs baseline: 1.0228x; 1.0228x over previous
//
#include <hip/hip_runtime.h>

#define NN 50000          // nodes
#define NE 800000         // edges (without self loops)
#define NE2 (NE + NN)     // edges + self loops
#define CSRN (NE + 2 * NN) // csr slots: per node [counter][self][reals]
#define FD 128            // input feature dim
#define HD 128            // hidden dim
#define NHD 4             // heads
#define OD 512            // heads * HD
#define NG 512            // graphs
#define BN_EPS 1e-5f

#define SCAN_CHUNK 2048
#define EB_CHUNK 4096
#define NB_F ((NE + EB_CHUNK - 1) / EB_CHUNK)      // 196 edge chunks
#define NBUCK ((NN + 511) / 512)                   // 98 node buckets (512 nodes)
#define NH (NBUCK * NB_F)                          // 19208 counters
#define NB2 ((NH + SCAN_CHUNK - 1) / SCAN_CHUNK)   // 10 scan blocks
#define CAPR 13312                                 // LDS stage ints (52KB)

#define XB_BLOCKS (NN * FD / 4 / 256)              // 6250
#define WG_BLOCKS (FD * HD / 256)                  // 64
#define WA_BLOCKS (HD * OD / 256)                  // 256
#define CP_XB0 7
#define CP_WG0 (CP_XB0 + XB_BLOCKS)
#define CP_WA0 (CP_WG0 + WG_BLOCKS)
#define CP_Z0  (CP_WA0 + WA_BLOCKS)      // 1 block: h0 zero row
#define CP_GS0 (CP_Z0 + 1)               // 3 blocks: gstart binary searches
#define CP_FZ0 (CP_GS0 + 3)              // 768 blocks: feat zero
#define CP_NB  (CP_FZ0 + 768)

typedef __attribute__((ext_vector_type(8))) short bfrag;   // 8 bf16 = 4 VGPRs
typedef __attribute__((ext_vector_type(4))) float f32x4;
typedef __attribute__((ext_vector_type(2))) float f32x2;
typedef unsigned short ushort_t;

__device__ inline ushort_t f2bf(float f) {               // RNE fp32->bf16
    unsigned int u = __float_as_uint(f);
    unsigned int r = (u + 0x7fffu + ((u >> 16) & 1u)) >> 16;
    return (ushort_t)r;
}
__device__ inline float bf2f_lo(unsigned int v) { return __uint_as_float(v << 16); }
__device__ inline float bf2f_hi(unsigned int v) { return __uint_as_float(v & 0xffff0000u); }

// ---------------- CSR build: bucket-staged, no global atomics ----------------
__global__ __launch_bounds__(256) void histA_k(const int* __restrict__ ei,
                                               int* __restrict__ hist) {
    __shared__ int h[NBUCK];
    int blk = blockIdx.x, t = threadIdx.x;
    for (int i = t; i < NBUCK; i += 256) h[i] = 0;
    __syncthreads();
    int e0 = blk * EB_CHUNK;
    for (int i = t; i < EB_CHUNK; i += 256) {
        int e = e0 + i;
        if (e < NE) atomicAdd(&h[ei[NE + e] >> 9], 1);
    }
    __syncthreads();
    for (int i = t; i < NBUCK; i += 256) hist[i * NB_F + blk] = h[i];
}

__global__ __launch_bounds__(256) void scanA2_k(const int* __restrict__ hist,
                                                int* __restrict__ bsum2) {
    __shared__ int red[256];
    int b = blockIdx.x, t = threadIdx.x;
    int base = b * SCAN_CHUNK + t * 8;
    int s = 0;
    #pragma unroll
    for (int i = 0; i < 8; ++i) { int idx = base + i; if (idx < NH) s += hist[idx]; }
    red[t] = s;
    __syncthreads();
    for (int off = 128; off; off >>= 1) {
        if (t < off) red[t] += red[t + off];
        __syncthreads();
    }
    if (t == 0) bsum2[b] = red[0];
}

__global__ __launch_bounds__(256) void scanC2_k(const int* __restrict__ hist,
                                                const int* __restrict__ bsum2,
                                                int* __restrict__ base) {
    __shared__ int red[256];
    __shared__ int boff_s;
    int b = blockIdx.x, t = threadIdx.x;
    if (t == 0) {
        int run = 0;
        for (int i = 0; i < b; ++i) run += bsum2[i];
        boff_s = run;
    }
    int bse = b * SCAN_CHUNK + t * 8;
    int v[8];
    int s = 0;
    #pragma unroll
    for (int i = 0; i < 8; ++i) {
        int idx = bse + i;
        v[i] = (idx < NH) ? hist[idx] : 0;
        s += v[i];
    }
    red[t] = s;
    __syncthreads();
    for (int off = 1; off < 256; off <<= 1) {
        int y = (t >= off) ? red[t - off] : 0;
        __syncthreads();
        red[t] += y;
        __syncthreads();
    }
    int run = boff_s + red[t] - s;
    #pragma unroll
    for (int i = 0; i < 8; ++i) {
        int idx = bse + i;
        if (idx < NH) { base[idx] = run; run += v[i]; }
    }
    if (b == 0 && t == 0) base[NH] = NE;
}

__global__ __launch_bounds__(256) void scatter2_k(const int* __restrict__ ei,
                                                  const int* __restrict__ base,
                                                  int2* __restrict__ ebuf) {
    __shared__ int cur[NBUCK];
    int blk = blockIdx.x, t = threadIdx.x;
    for (int i = t; i < NBUCK; i += 256) cur[i] = base[i * NB_F + blk];
    __syncthreads();
    int e0 = blk * EB_CHUNK;
    for (int i = t; i < EB_CHUNK; i += 256) {
        int e = e0 + i;
        if (e < NE) {
            int src = ei[e], dst = ei[NE + e];
            int pos = atomicAdd(&cur[dst >> 9], 1);
            ebuf[pos] = make_int2(src, dst);
        }
    }
}

__global__ __launch_bounds__(256) void bfill_k(const int2* __restrict__ ebuf,
                                               const int* __restrict__ base,
                                               int* __restrict__ rowptr,
                                               float* __restrict__ dis,
                                               int* __restrict__ csr) {
    __shared__ int cnt[512];
    __shared__ int pref[512];
    __shared__ int red[256];
    __shared__ int stage[CAPR];
    int b = blockIdx.x, t = threadIdx.x;
    int n0 = b * 512;
    int nn = min(512, NN - n0);
    int eb0 = base[b * NB_F];
    int eb1 = base[(b + 1) * NB_F];
    int ecnt = eb1 - eb0;
    int gbase = eb0 + 2 * n0;
    for (int i = t; i < nn; i += 256) cnt[i] = 0;
    __syncthreads();
    for (int e = eb0 + t; e < eb1; e += 256)
        atomicAdd(&cnt[ebuf[e].y - n0], 1);
    __syncthreads();
    int i0 = 2 * t, i1 = 2 * t + 1;
    int v0 = (i0 < nn) ? cnt[i0] + 2 : 0;
    int v1 = (i1 < nn) ? cnt[i1] + 2 : 0;
    int ps = v0 + v1;
    red[t] = ps;
    __syncthreads();
    for (int off = 1; off < 256; off <<= 1) {
        int y = (t >= off) ? red[t - off] : 0;
        __syncthreads();
        red[t] += y;
        __syncthreads();
    }
    int excl = red[t] - ps;
    if (i0 < nn) pref[i0] = excl;
    if (i1 < nn) pref[i1] = excl + v0;
    __syncthreads();
    int region = ecnt + 2 * nn;
    for (int i = t; i < nn; i += 256) {
        rowptr[n0 + i] = gbase + pref[i];
        dis[n0 + i] = rsqrtf((float)(cnt[i] + 1));
    }
    if (b == 0 && t == 0) rowptr[NN] = CSRN;
    __syncthreads();
    for (int i = t; i < nn; i += 256) cnt[i] = 0;
    __syncthreads();
    if (region <= CAPR) {
        for (int i = t; i < nn; i += 256) {
            int r = pref[i];
            stage[r] = 0;
            stage[r + 1] = n0 + i;
        }
        __syncthreads();
        for (int e = eb0 + t; e < eb1; e += 256) {
            int2 ed = ebuf[e];
            int l = ed.y - n0;
            int pos = atomicAdd(&cnt[l], 1);
            stage[pref[l] + 2 + pos] = ed.x;
        }
        __syncthreads();
        for (int i = t; i < region; i += 256) csr[gbase + i] = stage[i];
    } else {
        for (int i = t; i < nn; i += 256) {
            int r = gbase + pref[i];
            csr[r] = 0;
            csr[r + 1] = n0 + i;
        }
        __syncthreads();
        for (int e = eb0 + t; e < eb1; e += 256) {
            int2 ed = ebuf[e];
            int l = ed.y - n0;
            int pos = atomicAdd(&cnt[l], 1);
            csr[gbase + pref[l] + 2 + pos] = ed.x;
        }
    }
}

// ---------------- merged: BN affine + waT + casts + zero-row + gstart + feat zero ----------------
__global__ __launch_bounds__(256) void castprep_k(
    const float* __restrict__ b_gcn, const float* __restrict__ g2_gam,
    const float* __restrict__ g2_bet, const float* __restrict__ g2_mean,
    const float* __restrict__ g2_var, const float* __restrict__ b_gat,
    const float* __restrict__ g1_gam, const float* __restrict__ g1_bet,
    const float* __restrict__ g1_mean, const float* __restrict__ g1_var,
    float* __restrict__ Ag, float* __restrict__ Bg,
    float* __restrict__ Aa, float* __restrict__ Ba,
    const float* __restrict__ a_src, const float* __restrict__ a_dst,
    float* __restrict__ waT,
    const float* __restrict__ x, ushort_t* __restrict__ xb,
    const float* __restrict__ w_gcn, ushort_t* __restrict__ wgT,
    const float* __restrict__ w_gat, ushort_t* __restrict__ wgatT,
    ushort_t* __restrict__ h0b, const int* __restrict__ batch,
    int* __restrict__ gstart, float* __restrict__ feat) {
    int b = blockIdx.x, tid = threadIdx.x;
    if (b < 3) {
        int t = b * 256 + tid;
        if (t < HD) {
            float a = rsqrtf(g2_var[t] + BN_EPS) * g2_gam[t];
            Ag[t] = a;
            Bg[t] = (b_gcn[t] - g2_mean[t]) * a + g2_bet[t];
        } else if (t < HD + OD) {
            int d = t - HD;
            float a = rsqrtf(g1_var[d] + BN_EPS) * g1_gam[d];
            Aa[d] = a;
            Ba[d] = (b_gat[d] - g1_mean[d]) * a + g1_bet[d];
        }
    } else if (b < 7) {
        int t = (b - 3) * 256 + tid;       // 0..1023
        int k = t >> 3, j = t & 7, head = j & 3;
        const float* av = (j < 4 ? a_src : a_dst) + head * 128;
        const float* w = w_gat + (size_t)k * OD + head * 128;
        float s = 0.f;
        for (int d = 0; d < 128; ++d) s += w[d] * av[d];
        waT[j * 128 + k] = s;
    } else if (b < CP_WG0) {
        int t = (b - CP_XB0) * 256 + tid;
        float4 v = ((const float4*)x)[t];
        ushort_t o[4] = {f2bf(v.x), f2bf(v.y), f2bf(v.z), f2bf(v.w)};
        *(unsigned long long*)(xb + 4 * t) = *(unsigned long long*)o;
    } else if (b < CP_WA0) {
        int t = (b - CP_WG0) * 256 + tid;       // K=FD, N=HD
        int n = t / FD, k = t - n * FD;
        wgT[n * FD + k] = f2bf(w_gcn[k * HD + n]);
    } else if (b < CP_Z0) {
        int t = (b - CP_WA0) * 256 + tid;   // K=HD, N=OD
        int n = t / HD, k = t - n * HD;
        wgatT[n * HD + k] = f2bf(w_gat[k * OD + n]);
    } else if (b < CP_GS0) {
        if (tid < 64) ((unsigned int*)(h0b + (size_t)NN * HD))[tid] = 0u;
    } else if (b < CP_FZ0) {
        int g = (b - CP_GS0) * 256 + tid;
        if (g <= NG) {
            int lo = 0, hi = NN;
            while (lo < hi) { int mid = (lo + hi) >> 1; if (batch[mid] < g) lo = mid + 1; else hi = mid; }
            gstart[g] = lo;
        }
    } else {
        int t = (b - CP_FZ0) * 256 + tid;       // 768*256 threads, 4 floats each
        float4 z = make_float4(0.f, 0.f, 0.f, 0.f);
        *(float4*)(feat + 4 * (size_t)t) = z;
    }
}

// ---------------- bf16 MFMA GEMM: C[M,N] = A[M,128] @ B[128,N], bf16 out, opt row-scale
template <bool SCALE>
__global__ __launch_bounds__(256) void gemm_bf16_t(const ushort_t* __restrict__ A,
                                                   const ushort_t* __restrict__ BT,
                                                   const float* __restrict__ rowscale,
                                                   ushort_t* __restrict__ C,
                                                   int M, int N) {
    __shared__ short As[128][136];
    __shared__ short Bs[64][136];
    const int tid = threadIdx.x;
    const int m0 = blockIdx.x * 128;
    const int n0 = blockIdx.y * 64;

    #pragma unroll
    for (int i = 0; i < 8; ++i) {
        int c = tid + 256 * i;
        int row = c >> 4, off = (c & 15) * 8;
        bfrag v = (bfrag)0;
        if (m0 + row < M) v = *(const bfrag*)(A + (size_t)(m0 + row) * 128 + off);
        *(bfrag*)&As[row][off] = v;
    }
    #pragma unroll
    for (int i = 0; i < 4; ++i) {
        int c = tid + 256 * i;
        int row = c >> 4, off = (c & 15) * 8;
        *(bfrag*)&Bs[row][off] = *(const bfrag*)(BT + (size_t)(n0 + row) * 128 + off);
    }
    __syncthreads();

    const int w = tid >> 6;
    const int lr = tid & 15;
    const int kg = (tid & 63) >> 4;

    f32x4 acc[2][4];
    #pragma unroll
    for (int mi = 0; mi < 2; ++mi)
        #pragma unroll
        for (int ni = 0; ni < 4; ++ni) acc[mi][ni] = (f32x4)0.f;

    #pragma unroll
    for (int ks = 0; ks < 4; ++ks) {
        bfrag af[2], bb[4];
        #pragma unroll
        for (int mi = 0; mi < 2; ++mi)
            af[mi] = *(const bfrag*)&As[32 * w + 16 * mi + lr][32 * ks + 8 * kg];
        #pragma unroll
        for (int ni = 0; ni < 4; ++ni)
            bb[ni] = *(const bfrag*)&Bs[16 * ni + lr][32 * ks + 8 * kg];
        #pragma unroll
        for (int mi = 0; mi < 2; ++mi)
            #pragma unroll
            for (int ni = 0; ni < 4; ++ni)
                acc[mi][ni] = __builtin_amdgcn_mfma_f32_16x16x32_bf16(
                    af[mi], bb[ni], acc[mi][ni], 0, 0, 0);
    }

    #pragma unroll
    for (int mi = 0; mi < 2; ++mi) {
        #pragma unroll
        for (int r = 0; r < 4; ++r) {
            int row = m0 + 32 * w + 16 * mi + 4 * kg + r;
            if (row < M) {
                float sc = SCALE ? rowscale[row] : 1.f;
                #pragma unroll
                for (int ni = 0; ni < 4; ++ni) {
                    int col = n0 + 16 * ni + lr;
                    float v = acc[mi][ni][r];
                    if (SCALE) v *= sc;
                    C[(size_t)row * N + col] = f2bf(v);
                }
            }
        }
    }
}

// ---------------- per-head GEMM + BN + ReLU + fused pooling (atomic sadd/smax) ----------------
__global__ __launch_bounds__(256) void gemm_zp_k(const ushort_t* __restrict__ zb,
                                                 const ushort_t* __restrict__ wgatT,
                                                 const float* __restrict__ Aa,
                                                 const float* __restrict__ Ba,
                                                 const int* __restrict__ batch,
                                                 const int* __restrict__ gstart,
                                                 float* __restrict__ feat) {
    __shared__ short As[128][136];
    __shared__ short Bs[64][136];
    const int tid = threadIdx.x;
    const int head = blockIdx.z;
    const int m0 = blockIdx.x * 128;
    const int n0 = blockIdx.y * 64;
    const ushort_t* A = zb + (size_t)head * NN * HD;
    const ushort_t* BT = wgatT + (size_t)head * HD * HD;

    #pragma unroll
    for (int i = 0; i < 8; ++i) {
        int c = tid + 256 * i;
        int row = c >> 4, off = (c & 15) * 8;
        bfrag v = (bfrag)0;
        if (m0 + row < NN) v = *(const bfrag*)(A + (size_t)(m0 + row) * HD + off);
        *(bfrag*)&As[row][off] = v;
    }
    #pragma unroll
    for (int i = 0; i < 4; ++i) {
        int c = tid + 256 * i;
        int row = c >> 4, off = (c & 15) * 8;
        *(bfrag*)&Bs[row][off] = *(const bfrag*)(BT + (size_t)(n0 + row) * HD + off);
    }
    __syncthreads();

    const int w = tid >> 6;
    const int lr = tid & 15;
    const int kg = (tid & 63) >> 4;

    f32x4 acc[2][4];
    #pragma unroll
    for (int mi = 0; mi < 2; ++mi)
        #pragma unroll
        for (int ni = 0; ni < 4; ++ni) acc[mi][ni] = (f32x4)0.f;

    #pragma unroll
    for (int ks = 0; ks < 4; ++ks) {
        bfrag af[2], bb[4];
        #pragma unroll
        for (int mi = 0; mi < 2; ++mi)
            af[mi] = *(const bfrag*)&As[32 * w + 16 * mi + lr][32 * ks + 8 * kg];
        #pragma unroll
        for (int ni = 0; ni < 4; ++ni)
            bb[ni] = *(const bfrag*)&Bs[16 * ni + lr][32 * ks + 8 * kg];
        #pragma unroll
        for (int mi = 0; mi < 2; ++mi)
            #pragma unroll
            for (int ni = 0; ni < 4; ++ni)
                acc[mi][ni] = __builtin_amdgcn_mfma_f32_16x16x32_bf16(
                    af[mi], bb[ni], acc[mi][ni], 0, 0, 0);
    }

    __syncthreads();
    float (*vals)[65] = reinterpret_cast<float(*)[65]>(&As[0][0]);
    float (*psum)[64] = reinterpret_cast<float(*)[64]>(&Bs[0][0]);
    float (*pmax)[64] = reinterpret_cast<float(*)[64]>(&Bs[8][0]);

    #pragma unroll
    for (int mi = 0; mi < 2; ++mi) {
        #pragma unroll
        for (int r = 0; r < 4; ++r) {
            int lrow = 32 * w + 16 * mi + 4 * kg + r;
            int row = m0 + lrow;
            if (row < NN) {
                #pragma unroll
                for (int ni = 0; ni < 4; ++ni) {
                    int gc = 128 * head + n0 + 16 * ni + lr;
                    float v = fmaf(acc[mi][ni][r], Aa[gc], Ba[gc]);
                    vals[lrow][16 * ni + lr] = fmaxf(v, 0.f);
                }
            }
        }
    }
    __syncthreads();

    int rmax = min(128, NN - m0);
    int gfirst = batch[m0];
    int glast = batch[m0 + rmax - 1];
    int c = tid & 63, part = tid >> 6;
    for (int gg = gfirst; gg <= glast; ++gg) {
        int s = max(gstart[gg], m0) - m0;
        int e = min(gstart[gg + 1], m0 + rmax) - m0;
        float sm = 0.f, mx = 0.f;
        for (int r = s + part; r < e; r += 4) {
            float v = vals[r][c];
            sm += v;
            mx = fmaxf(mx, v);
        }
        psum[part][c] = sm;
        pmax[part][c] = mx;
        __syncthreads();
        if (part == 0) {
            float ts = (psum[0][c] + psum[1][c]) + (psum[2][c] + psum[3][c]);
            float tm = fmaxf(fmaxf(pmax[0][c], pmax[1][c]), fmaxf(pmax[2][c], pmax[3][c]));
            if (e > s) {
                int gc = 128 * head + n0 + c;
                atomicAdd(&feat[(size_t)gg * 1536 + gc], ts);
                atomicMax((int*)&feat[(size_t)gg * 1536 + 512 + gc], __float_as_int(tm));
            }
        }
        __syncthreads();
    }
}

// ---------------- GCN aggregate + BN + ReLU + fused attention dots ----------------
__global__ __launch_bounds__(256) void gcn_agg4_k(
    const ushort_t* __restrict__ h0, const int* __restrict__ rowptr,
    const int* __restrict__ csr, const float* __restrict__ dis,
    const float* __restrict__ Ag, const float* __restrict__ Bg,
    const float* __restrict__ waT,
    ushort_t* __restrict__ h, float* __restrict__ asrc, float* __restrict__ adst) {
    int lane = threadIdx.x & 63;
    int g = lane >> 4;
    int sl = lane & 15;
    int sl8 = sl * 8;
    int n = __builtin_amdgcn_readfirstlane((int)(blockIdx.x * 4) + (int)(threadIdx.x >> 6));
    int r0 = __builtin_amdgcn_readfirstlane(rowptr[n]) + 1;   // skip counter slot
    int r1 = __builtin_amdgcn_readfirstlane(rowptr[n + 1]);
    const uint4* h0_u4 = (const uint4*)h0;
    f32x2 a2[4];
    #pragma unroll
    for (int q = 0; q < 4; ++q) a2[q] = (f32x2)0.f;
    uint4 hv[2];

#define GLOAD(i, BASE) { int _e = (BASE) + g; int _sv = csr[_e]; \
    int _s = _e < r1 ? _sv : NN; \
    hv[i] = h0_u4[(unsigned)_s * 16u + (unsigned)sl]; }
#define GACC(i) { \
    f32x2 _f0 = {bf2f_lo(hv[i].x), bf2f_hi(hv[i].x)}; \
    f32x2 _f1 = {bf2f_lo(hv[i].y), bf2f_hi(hv[i].y)}; \
    f32x2 _f2 = {bf2f_lo(hv[i].z), bf2f_hi(hv[i].z)}; \
    f32x2 _f3 = {bf2f_lo(hv[i].w), bf2f_hi(hv[i].w)}; \
    a2[0] += _f0; a2[1] += _f1; a2[2] += _f2; a2[3] += _f3; }

    GLOAD(0, r0) GLOAD(1, r0 + 4)
    for (int base = r0; base < r1; base += 8) {
        GACC(0) GLOAD(0, base + 8)
        GACC(1) GLOAD(1, base + 12)
    }
#undef GLOAD
#undef GACC

    #pragma unroll
    for (int q = 0; q < 4; ++q) {
        f32x2 v = a2[q];
        v.x += __shfl_xor(v.x, 16); v.x += __shfl_xor(v.x, 32);
        v.y += __shfl_xor(v.y, 16); v.y += __shfl_xor(v.y, 32);
        a2[q] = v;
    }
    float a[8] = {a2[0].x, a2[0].y, a2[1].x, a2[1].y,
                  a2[2].x, a2[2].y, a2[3].x, a2[3].y};
    float t = dis[n];
    float4 A0 = *(const float4*)(Ag + sl8);
    float4 A1 = *(const float4*)(Ag + sl8 + 4);
    float4 B0 = *(const float4*)(Bg + sl8);
    float4 B1 = *(const float4*)(Bg + sl8 + 4);
    float o[8];
    o[0] = fmaxf(fmaf(a[0] * t, A0.x, B0.x), 0.f);
    o[1] = fmaxf(fmaf(a[1] * t, A0.y, B0.y), 0.f);
    o[2] = fmaxf(fmaf(a[2] * t, A0.z, B0.z), 0.f);
    o[3] = fmaxf(fmaf(a[3] * t, A0.w, B0.w), 0.f);
    o[4] = fmaxf(fmaf(a[4] * t, A1.x, B1.x), 0.f);
    o[5] = fmaxf(fmaf(a[5] * t, A1.y, B1.y), 0.f);
    o[6] = fmaxf(fmaf(a[6] * t, A1.z, B1.z), 0.f);
    o[7] = fmaxf(fmaf(a[7] * t, A1.w, B1.w), 0.f);
    if (g == 0) {
        uint4 pk;
        pk.x = (unsigned int)f2bf(o[0]) | ((unsigned int)f2bf(o[1]) << 16);
        pk.y = (unsigned int)f2bf(o[2]) | ((unsigned int)f2bf(o[3]) << 16);
        pk.z = (unsigned int)f2bf(o[4]) | ((unsigned int)f2bf(o[5]) << 16);
        pk.w = (unsigned int)f2bf(o[6]) | ((unsigned int)f2bf(o[7]) << 16);
        *(uint4*)(h + (size_t)n * HD + sl8) = pk;
    }
    const float* w0p = waT + (2 * g) * 128 + sl8;
    const float* w1p = waT + (2 * g + 1) * 128 + sl8;
    float4 wA0 = *(const float4*)(w0p);
    float4 wA1 = *(const float4*)(w0p + 4);
    float4 wB0 = *(const float4*)(w1p);
    float4 wB1 = *(const float4*)(w1p + 4);
    float p0 = o[0] * wA0.x + o[1] * wA0.y + o[2] * wA0.z + o[3] * wA0.w
             + o[4] * wA1.x + o[5] * wA1.y + o[6] * wA1.z + o[7] * wA1.w;
    float p1 = o[0] * wB0.x + o[1] * wB0.y + o[2] * wB0.z + o[3] * wB0.w
             + o[4] * wB1.x + o[5] * wB1.y + o[6] * wB1.z + o[7] * wB1.w;
    #pragma unroll
    for (int off2 = 1; off2 < 16; off2 <<= 1) {
        p0 += __shfl_xor(p0, off2);
        p1 += __shfl_xor(p1, off2);
    }
    if (sl == 0) {
        int j0 = 2 * g;
        float* d0 = (j0 < 4) ? asrc : adst;
        float* d1 = (j0 + 1 < 4) ? asrc : adst;
        d0[n * 4 + (j0 & 3)] = p0;
        d1[n * 4 + ((j0 + 1) & 3)] = p1;
    }
}

// ---------------- fused GAT: LDS p-phase + weighted gather + reduce-scatter ----------------
__global__ __launch_bounds__(256) void zgather3_k(
    const ushort_t* __restrict__ h, const int* __restrict__ rowptr,
    const int* __restrict__ csr, const float* __restrict__ asrc,
    const float* __restrict__ adst, ushort_t* __restrict__ zb) {
    __shared__ float4 p4s[4][64];
    __shared__ int sis[4][64];
    int wv = threadIdx.x >> 6;
    int lane = threadIdx.x & 63;
    int g = lane >> 4;
    int sl = lane & 15;
    int sl8 = sl * 8;
    int n = __builtin_amdgcn_readfirstlane((int)(blockIdx.x * 4) + wv);
    int r0 = __builtin_amdgcn_readfirstlane(rowptr[n]) + 1;   // skip counter slot
    int r1 = __builtin_amdgcn_readfirstlane(rowptr[n + 1]);
    const uint4* h_u4 = (const uint4*)h;
    float4 ad = *(const float4*)(adst + 4 * n);     // uniform

    f32x2 acc[4][4];                // [head][dim-pair]
    #pragma unroll
    for (int hh = 0; hh < 4; ++hh)
        #pragma unroll
        for (int q = 0; q < 4; ++q) acc[hh][q] = (f32x2)0.f;
    f32x2 s01 = (f32x2)0.f, s23 = (f32x2)0.f;

    uint4 hv[2];
    f32x2 pa[2], pb[2];

#define ZLOAD(i, ST) { int _idx = min((ST) * 4 + g, 63); \
    float4 _p = p4s[wv][_idx]; \
    int _s = sis[wv][_idx]; \
    pa[i].x = _p.x; pa[i].y = _p.y; pb[i].x = _p.z; pb[i].y = _p.w; \
    hv[i] = h_u4[(unsigned)_s * 16u + (unsigned)sl]; }
#define ZACC(i) { \
    f32x2 _f0 = {bf2f_lo(hv[i].x), bf2f_hi(hv[i].x)}; \
    f32x2 _f1 = {bf2f_lo(hv[i].y), bf2f_hi(hv[i].y)}; \
    f32x2 _f2 = {bf2f_lo(hv[i].z), bf2f_hi(hv[i].z)}; \
    f32x2 _f3 = {bf2f_lo(hv[i].w), bf2f_hi(hv[i].w)}; \
    s01 += pa[i]; s23 += pb[i]; \
    f32x2 _p0 = {pa[i].x, pa[i].x}; \
    f32x2 _p1 = {pa[i].y, pa[i].y}; \
    f32x2 _p2 = {pb[i].x, pb[i].x}; \
    f32x2 _p3 = {pb[i].y, pb[i].y}; \
    acc[0][0] = __builtin_elementwise_fma(_p0, _f0, acc[0][0]); \
    acc[0][1] = __builtin_elementwise_fma(_p0, _f1, acc[0][1]); \
    acc[0][2] = __builtin_elementwise_fma(_p0, _f2, acc[0][2]); \
    acc[0][3] = __builtin_elementwise_fma(_p0, _f3, acc[0][3]); \
    acc[1][0] = __builtin_elementwise_fma(_p1, _f0, acc[1][0]); \
    acc[1][1] = __builtin_elementwise_fma(_p1, _f1, acc[1][1]); \
    acc[1][2] = __builtin_elementwise_fma(_p1, _f2, acc[1][2]); \
    acc[1][3] = __builtin_elementwise_fma(_p1, _f3, acc[1][3]); \
    acc[2][0] = __builtin_elementwise_fma(_p2, _f0, acc[2][0]); \
    acc[2][1] = __builtin_elementwise_fma(_p2, _f1, acc[2][1]); \
    acc[2][2] = __builtin_elementwise_fma(_p2, _f2, acc[2][2]); \
    acc[2][3] = __builtin_elementwise_fma(_p2, _f3, acc[2][3]); \
    acc[3][0] = __builtin_elementwise_fma(_p3, _f0, acc[3][0]); \
    acc[3][1] = __builtin_elementwise_fma(_p3, _f1, acc[3][1]); \
    acc[3][2] = __builtin_elementwise_fma(_p3, _f2, acc[3][2]); \
    acc[3][3] = __builtin_elementwise_fma(_p3, _f3, acc[3][3]); }

    for (int base = r0; base < r1; base += 64) {
        {
            int e = base + lane;
            bool v = e < r1;
            int sv = csr[e];                 // csr padded +64
            int s = v ? sv : 0;
            float4 as = *(const float4*)(asrc + 4 * (size_t)s);
            f32x2 x01 = {as.x + ad.x, as.y + ad.y};
            f32x2 x23 = {as.z + ad.z, as.w + ad.w};
            f32x2 l01 = __builtin_elementwise_max(x01, 0.2f * x01);
            f32x2 l23 = __builtin_elementwise_max(x23, 0.2f * x23);
            float4 p;
            p.x = v ? __expf(l01.x) : 0.f;
            p.y = v ? __expf(l01.y) : 0.f;
            p.z = v ? __expf(l23.x) : 0.f;
            p.w = v ? __expf(l23.y) : 0.f;
            p4s[wv][lane] = p;
            sis[wv][lane] = s;
        }
        int rem = r1 - base; if (rem > 64) rem = 64;
        int nsteps = (rem + 3) >> 2;
        ZLOAD(0, 0) ZLOAD(1, 1)
        for (int st = 0; st < nsteps; st += 2) {
            ZACC(0) ZLOAD(0, st + 2)
            ZACC(1) ZLOAD(1, st + 3)
        }
    }
#undef ZLOAD
#undef ZACC

    bool gb0 = (g & 1) != 0;
    bool gb1 = (g & 2) != 0;
    f32x2 tot[4];
    #pragma unroll
    for (int q = 0; q < 4; ++q) {
        f32x2 sA = gb0 ? acc[0][q] : acc[1][q];
        f32x2 sB = gb0 ? acc[2][q] : acc[3][q];
        f32x2 rA, rB;
        rA.x = __shfl_xor(sA.x, 16); rA.y = __shfl_xor(sA.y, 16);
        rB.x = __shfl_xor(sB.x, 16); rB.y = __shfl_xor(sB.y, 16);
        f32x2 kA = (gb0 ? acc[1][q] : acc[0][q]) + rA;
        f32x2 kB = (gb0 ? acc[3][q] : acc[2][q]) + rB;
        f32x2 s2 = gb1 ? kA : kB;
        f32x2 r2;
        r2.x = __shfl_xor(s2.x, 32); r2.y = __shfl_xor(s2.y, 32);
        tot[q] = (gb1 ? kB : kA) + r2;
    }
    float sA1 = gb0 ? s01.x : s01.y;
    float sB1 = gb0 ? s23.x : s23.y;
    float rA1 = __shfl_xor(sA1, 16);
    float rB1 = __shfl_xor(sB1, 16);
    float kAs = (gb0 ? s01.y : s01.x) + rA1;
    float kBs = (gb0 ? s23.y : s23.x) + rB1;
    float s2s = gb1 ? kAs : kBs;
    float r2s = __shfl_xor(s2s, 32);
    float stot = (gb1 ? kBs : kAs) + r2s;
    float invg = 1.f / (stot + 1e-16f);

    unsigned int pkc[4];
    #pragma unroll
    for (int q = 0; q < 4; ++q) {
        f32x2 v = tot[q] * invg;
        pkc[q] = (unsigned int)f2bf(v.x) | ((unsigned int)f2bf(v.y) << 16);
    }
    uint4 pk = {pkc[0], pkc[1], pkc[2], pkc[3]};
    *(uint4*)(zb + (size_t)g * NN * HD + (size_t)n * HD + sl8) = pk;
}

// ---------------- head: smean from sadd/cnt, GEMV + sigmoid ----------------
__global__ __launch_bounds__(256) void head2_k(const float* __restrict__ feat,
                                               const int* __restrict__ gstart,
                                               const float* __restrict__ w_lin,
                                               const float* __restrict__ b_lin,
                                               float* __restrict__ out) {
    __shared__ float fs[1536];
    __shared__ float red[256];
    int g = blockIdx.x, t = threadIdx.x;
    int cnt = gstart[g + 1] - gstart[g];
    float inv = cnt > 0 ? 1.f / (float)cnt : 0.f;
    for (int i = t; i < 512; i += 256) {
        float sa = feat[(size_t)g * 1536 + i];
        float mx = feat[(size_t)g * 1536 + 512 + i];
        fs[i] = sa;
        fs[512 + i] = mx;
        fs[1024 + i] = sa * inv;
    }
    __syncthreads();
    int o = t & 15, part = t >> 4;
    float s = 0.f;
    int kbeg = part * 96;
    for (int k = kbeg; k < kbeg + 96; ++k) s += fs[k] * w_lin[k * 16 + o];
    red[t] = s;
    __syncthreads();
    if (t < 16) {
        float tot = b_lin[o];
        for (int p = 0; p < 16; ++p) tot += red[p * 16 + o];
        out[g * 16 + o] = 1.f / (1.f + __expf(-tot));
    }
}

extern "C" void kernel_launch(void* const* d_in, const int* in_sizes, int n_in,
                              void* d_out, int out_size, void* d_ws, size_t ws_size,
                              hipStream_t stream) {
    const float* x       = (const float*)d_in[0];
    const int*   ei      = (const int*)d_in[1];
    const int*   batch   = (const int*)d_in[2];
    const float* w_gcn   = (const float*)d_in[3];
    const float* b_gcn   = (const float*)d_in[4];
    const float* g2_gam  = (const float*)d_in[5];
    const float* g2_bet  = (const float*)d_in[6];
    const float* g2_mean = (const float*)d_in[7];
    const float* g2_var  = (const float*)d_in[8];
    const float* w_gat   = (const float*)d_in[9];
    const float* a_src   = (const float*)d_in[10];
    const float* a_dst   = (const float*)d_in[11];
    const float* b_gat   = (const float*)d_in[12];
    const float* g1_gam  = (const float*)d_in[13];
    const float* g1_bet  = (const float*)d_in[14];
    const float* g1_mean = (const float*)d_in[15];
    const float* g1_var  = (const float*)d_in[16];
    const float* w_lin   = (const float*)d_in[17];
    const float* b_lin   = (const float*)d_in[18];
    float* out = (float*)d_out;

    char* ws = (char*)d_ws;
    size_t off = 0;
    auto alloc = [&](size_t bytes) -> void* {
        void* p = ws + off;
        off += (bytes + 255) & ~(size_t)255;
        return p;
    };
    int* hist       = (int*)alloc((size_t)NH * 4);
    int* bsum2      = (int*)alloc((size_t)NB2 * 4);
    int* base       = (int*)alloc((size_t)(NH + 1) * 4);
    int2* ebuf      = (int2*)alloc((size_t)NE * 8);
    int* rowptr     = (int*)alloc((size_t)(NN + 1) * 4);
    int* csr        = (int*)alloc((size_t)(CSRN + 64) * 4);  // +64 pad: unclamped slot reads
    int* gstart     = (int*)alloc((size_t)(NG + 1) * 4);
    float* dis      = (float*)alloc((size_t)NN * 4);
    ushort_t* xb    = (ushort_t*)alloc((size_t)NN * FD * 2);
    ushort_t* wgT   = (ushort_t*)alloc((size_t)FD * HD * 2);
    ushort_t* wgatT = (ushort_t*)alloc((size_t)HD * OD * 2);
    ushort_t* h0b   = (ushort_t*)alloc((size_t)(NN + 1) * HD * 2);   // +1 zero row
    ushort_t* hb    = (ushort_t*)alloc((size_t)NN * HD * 2);
    ushort_t* zb    = (ushort_t*)alloc((size_t)NHD * NN * HD * 2);
    float* asrc     = (float*)alloc((size_t)NN * 4 * 4);
    float* adst     = (float*)alloc((size_t)NN * 4 * 4);
    float* waT      = (float*)alloc((size_t)8 * 128 * 4);
    float* Ag       = (float*)alloc((size_t)HD * 4);
    float* Bg       = (float*)alloc((size_t)HD * 4);
    float* Aa       = (float*)alloc((size_t)OD * 4);
    float* Ba       = (float*)alloc((size_t)OD * 4);
    float* feat     = (float*)alloc((size_t)NG * 1536 * 4);

    // CSR build: bucket-staged, no global atomics
    histA_k<<<NB_F, 256, 0, stream>>>(ei, hist);
    scanA2_k<<<NB2, 256, 0, stream>>>(hist, bsum2);
    scanC2_k<<<NB2, 256, 0, stream>>>(hist, bsum2, base);
    scatter2_k<<<NB_F, 256, 0, stream>>>(ei, base, ebuf);
    bfill_k<<<NBUCK, 256, 0, stream>>>(ebuf, base, rowptr, dis, csr);

    // merged BN affine + waT + casts + h0 zero-row + gstart + feat zero
    castprep_k<<<CP_NB, 256, 0, stream>>>(
        b_gcn, g2_gam, g2_bet, g2_mean, g2_var,
        b_gat, g1_gam, g1_bet, g1_mean, g1_var,
        Ag, Bg, Aa, Ba, a_src, a_dst, waT,
        x, xb, w_gcn, wgT, w_gat, wgatT, h0b, batch, gstart, feat);

    // GCN linear: h0' = dis-row-scaled (x @ w_gcn)   (bf16 MFMA)
    gemm_bf16_t<true><<<dim3((NN + 127) / 128, HD / 64), 256, 0, stream>>>(
        xb, wgT, dis, h0b, NN, HD);

    // GCN aggregate + BN2 + ReLU + attention dots (wave per node)
    gcn_agg4_k<<<NN / 4, 256, 0, stream>>>(h0b, rowptr, csr, dis, Ag, Bg, waT,
                                           hb, asrc, adst);

    // fused GAT softmax + gather (wave per node, LDS p-phase)
    zgather3_k<<<NN / 4, 256, 0, stream>>>(hb, rowptr, csr, asrc, adst, zb);

    // per-head GEMM + BN1 + ReLU + fused pooling -> feat (atomics)
    gemm_zp_k<<<dim3((NN + 127) / 128, HD / 64, NHD), 256, 0, stream>>>(
        zb, wgatT, Aa, Ba, batch, gstart, feat);

    // head (smean derived from sadd/cnt)
    head2_k<<<NG, 256, 0, stream>>>(feat, gstart, w_lin, b_lin, out);
}